// Round 1
// baseline (194.201 us; speedup 1.0000x reference)
//
#include <hip/hip_runtime.h>

typedef __attribute__((ext_vector_type(8))) short bf16x8;
typedef __attribute__((ext_vector_type(4))) float floatx4;

#define T_TREES 20
#define N_NODES 32      // padded (31 real internal nodes)
#define F_DIM 128
#define M_TILE 128
#define SP_STRIDE 132   // 33 dwords*4: odd-ish stride, 2-way max conflict on reads

__device__ __forceinline__ short f2bf(float f) {
    unsigned u = __float_as_uint(f);
    u += 0x7fffu + ((u >> 16) & 1u);   // RNE
    return (short)(u >> 16);
}

// ---------------- prep: masked bf16 weights, padded bias, scaled leaf class-0 values
__global__ void nrf_prep(const float* __restrict__ sw, const float* __restrict__ sb,
                         const float* __restrict__ ll, const float* __restrict__ tw,
                         const float* __restrict__ fm,
                         short* __restrict__ w_all, float* __restrict__ bias_p,
                         float* __restrict__ lv0) {
    int t = blockIdx.x, tid = threadIdx.x;
    // tree-weight softmax (tiny, redundant per block)
    float m = -1e30f;
    for (int i = 0; i < T_TREES; ++i) m = fmaxf(m, tw[i]);
    float s = 0.f;
    for (int i = 0; i < T_TREES; ++i) s += __expf(tw[i] - m);
    float wt = __expf(tw[t] - m) / s;

    const float* fmt = fm + t * F_DIM;
    const float* swt = sw + t * 31 * F_DIM;
    for (int idx = tid; idx < N_NODES * F_DIM; idx += blockDim.x) {
        int n = idx >> 7, f = idx & 127;
        float v = (n < 31) ? swt[n * F_DIM + f] * fmt[f] : 0.f;
        w_all[t * (N_NODES * F_DIM) + idx] = f2bf(v);
    }
    if (tid < N_NODES) {
        bias_p[t * N_NODES + tid] = (tid < 31) ? sb[t * 31 + tid] : 0.f;
        float a = ll[(t * 32 + tid) * 2 + 0], bb = ll[(t * 32 + tid) * 2 + 1];
        float mx = fmaxf(a, bb);
        float e0 = __expf(a - mx), e1 = __expf(bb - mx);
        lv0[t * N_NODES + tid] = wt * e0 / (e0 + e1);
    }
}

// ---------------- main: per-block 128 samples, fused GEMM+sigmoid+leaf-probs+reduce
__global__ __launch_bounds__(256) void nrf_main(const float* __restrict__ x,
        const short* __restrict__ w_all, const float* __restrict__ bias_p,
        const float* __restrict__ lv0, float* __restrict__ out) {
    __shared__ float sp[N_NODES * SP_STRIDE];     // transposed: sp[node][row]
    __shared__ float lv_s[T_TREES * N_NODES];
    __shared__ float bias_s[T_TREES * N_NODES];
    __shared__ float red[M_TILE];

    int tid = threadIdx.x;
    int wave = tid >> 6, lane = tid & 63;
    int q = lane >> 4, c16 = lane & 15;

    for (int i = tid; i < T_TREES * N_NODES; i += 256) { lv_s[i] = lv0[i]; bias_s[i] = bias_p[i]; }

    // A fragments: x is reused by all 20 trees -> load once, hold in registers.
    // A-layout: m = lane&15, k = quad*8 + j  => 8 contiguous fp32 per frag.
    int m0 = wave * 32;
    int rowBase = blockIdx.x * M_TILE;
    bf16x8 afrag[2][4];
    #pragma unroll
    for (int mi = 0; mi < 2; ++mi) {
        const float* xr = x + (size_t)(rowBase + m0 + mi * 16 + c16) * F_DIM;
        #pragma unroll
        for (int ks = 0; ks < 4; ++ks) {
            const float4* p = (const float4*)(xr + ks * 32 + q * 8);
            float4 f0 = p[0], f1 = p[1];
            bf16x8 v;
            v[0]=f2bf(f0.x); v[1]=f2bf(f0.y); v[2]=f2bf(f0.z); v[3]=f2bf(f0.w);
            v[4]=f2bf(f1.x); v[5]=f2bf(f1.y); v[6]=f2bf(f1.z); v[7]=f2bf(f1.w);
            afrag[mi][ks] = v;
        }
    }

    int b = tid & 127, h = tid >> 7;   // h: which half of the tree (leaves 0-15 vs 16-31)
    float acc0 = 0.f;                  // class-0 accumulator over trees
    __syncthreads();                   // lv_s / bias_s ready

    for (int t = 0; t < T_TREES; ++t) {
        // B fragments from global (L2-resident): B-layout n=lane&15, k=quad*8+j
        bf16x8 bfrag[2][4];
        const short* wt = w_all + t * (N_NODES * F_DIM);
        #pragma unroll
        for (int ni = 0; ni < 2; ++ni) {
            const short* wr = wt + (ni * 16 + c16) * F_DIM;
            #pragma unroll
            for (int ks = 0; ks < 4; ++ks)
                bfrag[ni][ks] = *(const bf16x8*)(wr + ks * 32 + q * 8);
        }
        floatx4 acc[2][2];
        #pragma unroll
        for (int mi = 0; mi < 2; ++mi)
            #pragma unroll
            for (int ni = 0; ni < 2; ++ni)
                acc[mi][ni] = (floatx4){0.f, 0.f, 0.f, 0.f};
        #pragma unroll
        for (int ks = 0; ks < 4; ++ks)
            #pragma unroll
            for (int mi = 0; mi < 2; ++mi)
                #pragma unroll
                for (int ni = 0; ni < 2; ++ni)
                    acc[mi][ni] = __builtin_amdgcn_mfma_f32_16x16x32_bf16(
                        afrag[mi][ks], bfrag[ni][ks], acc[mi][ni], 0, 0, 0);

        __syncthreads();   // previous tree's leaf reads of sp are done

        // epilogue: bias + sigmoid, store transposed (4 consecutive rows => b128 write)
        #pragma unroll
        for (int ni = 0; ni < 2; ++ni) {
            int col = ni * 16 + c16;
            float bv = bias_s[t * N_NODES + col];
            #pragma unroll
            for (int mi = 0; mi < 2; ++mi) {
                float4 v;
                v.x = 1.f / (1.f + __expf(-(acc[mi][ni][0] + bv)));
                v.y = 1.f / (1.f + __expf(-(acc[mi][ni][1] + bv)));
                v.z = 1.f / (1.f + __expf(-(acc[mi][ni][2] + bv)));
                v.w = 1.f / (1.f + __expf(-(acc[mi][ni][3] + bv)));
                *(float4*)&sp[col * SP_STRIDE + m0 + mi * 16 + q * 4] = v;
            }
        }
        __syncthreads();

        // leaf phase: thread handles sample b, subtree h (root's child 1+h)
        float r[16];
        float s0 = sp[b];                         // node 0 sigmoid
        r[0] = h ? s0 : 1.f - s0;                 // node 1 = left (1-g), node 2 = right (g)
        #pragma unroll
        for (int d = 1; d < 5; ++d) {
            int cnt = 1 << (d - 1);
            int lb = (1 << d) - 1 + h * cnt;      // first abs node of this level in subtree
            #pragma unroll
            for (int i = cnt - 1; i >= 0; --i) {  // descending: no clobber of r[i]
                float g = sp[(lb + i) * SP_STRIDE + b];
                float ri = r[i];
                r[2 * i + 1] = ri * g;            // right child (abs even)
                r[2 * i]     = ri * (1.f - g);    // left child (abs odd)
            }
        }
        const float* lvt = &lv_s[t * N_NODES + h * 16];
        #pragma unroll
        for (int i = 0; i < 16; ++i) acc0 += r[i] * lvt[i];
    }

    // combine the two subtree halves; out1 = 1 - out0 (all prob masses sum to 1)
    __syncthreads();
    if (h) red[b] = acc0;
    __syncthreads();
    if (!h) {
        float tot = acc0 + red[b];
        float2 o; o.x = tot; o.y = 1.f - tot;
        *(float2*)(out + (size_t)(rowBase + b) * 2) = o;
    }
}

extern "C" void kernel_launch(void* const* d_in, const int* in_sizes, int n_in,
                              void* d_out, int out_size, void* d_ws, size_t ws_size,
                              hipStream_t stream) {
    const float* x  = (const float*)d_in[0];
    const float* sw = (const float*)d_in[1];
    const float* sb = (const float*)d_in[2];
    const float* ll = (const float*)d_in[3];
    const float* tw = (const float*)d_in[4];
    const float* fm = (const float*)d_in[5];
    float* out = (float*)d_out;

    short* w_all  = (short*)d_ws;                         // 20*32*128*2 = 163840 B
    float* bias_p = (float*)((char*)d_ws + 163840);       // 2560 B
    float* lv0    = (float*)((char*)d_ws + 166400);       // 2560 B

    nrf_prep<<<T_TREES, 128, 0, stream>>>(sw, sb, ll, tw, fm, w_all, bias_p, lv0);

    int B = in_sizes[0] / F_DIM;                          // 131072
    nrf_main<<<B / M_TILE, 256, 0, stream>>>(x, w_all, bias_p, lv0, out);
}